// Round 6
// baseline (502.010 us; speedup 1.0000x reference)
//
#include <hip/hip_runtime.h>

typedef __attribute__((ext_vector_type(8))) short short8;
typedef __attribute__((ext_vector_type(4))) short short4v;
typedef __attribute__((ext_vector_type(4))) float f32x4;
typedef unsigned short u16;

__device__ __forceinline__ u16 f2bf(float f) {
    union { float f; unsigned u; } v; v.f = f;
    unsigned r = v.u + 0x7FFFu + ((v.u >> 16) & 1u);
    return (u16)(r >> 16);
}
__device__ __forceinline__ float bf2f(u16 h) {
    union { unsigned u; float f; } v; v.u = ((unsigned)h) << 16;
    return v.f;
}
__device__ __forceinline__ void split2(float f, u16& h, u16& l) {
    h = f2bf(f);
    l = f2bf(f - bf2f(h));
}
// 8-byte-aligned LDS frag load
__device__ __forceinline__ short8 ld8(const u16* p) {
    short4v a = *(const short4v*)p;
    short4v b = *(const short4v*)(p + 4);
    short8 r;
    r[0] = a[0]; r[1] = a[1]; r[2] = a[2]; r[3] = a[3];
    r[4] = b[0]; r[5] = b[1]; r[6] = b[2]; r[7] = b[3];
    return r;
}
#define MFMA(A, B, C) __builtin_amdgcn_mfma_f32_16x16x32_bf16(A, B, C, 0, 0, 0)
#define PRIO1() __builtin_amdgcn_s_setprio(1)
#define PRIO0() __builtin_amdgcn_s_setprio(0)

// ---------------- D1: zero A32 + Wc1 split (cell GEMM's dependency) ----------------
__global__ __launch_bounds__(256) void k_pre(int4* __restrict__ A32z, int nz4,
        const float* __restrict__ Wc1, u16* __restrict__ Wc1h, u16* __restrict__ Wc1l) {
    int i = blockIdx.x * 256 + threadIdx.x;
    if (i < nz4) { A32z[i] = make_int4(0, 0, 0, 0); return; }
    i -= nz4;
    if (i >= 131072) return;
    int f = i >> 10, k = i & 1023;
    float v = (k < 1000) ? Wc1[(size_t)k * 128 + f] : 0.f;
    u16 h, l; split2(v, h, l);
    Wc1h[i] = h; Wc1l[i] = l;
}

// ---------------- D2: cell1 GEMM blocks + edge-count atomics + remaining splits ----
// blocks [0, CELLB): cell1 = relu(cf @ Wc1 + bc1), 64 rows/block (512 thr)
// blocks [CELLB, CELLB+NCNT): edge counting, 512 edges/block
// blocks [CELLB+NCNT, ...): weight splits W1,W2,W3,Wd,Wc2,Wm1,Wm2 (81920 elems)
__global__ __launch_bounds__(512, 8) void k_mix(
        const int* __restrict__ ei, unsigned* __restrict__ A32, int E, int NCNT,
        const float* __restrict__ cf,
        const u16* __restrict__ Wc1h, const u16* __restrict__ Wc1l,
        const float* __restrict__ bc1, float* __restrict__ cell1, int CELLB,
        const float* __restrict__ W1, u16* __restrict__ W1h, u16* __restrict__ W1l,
        const float* __restrict__ W2, u16* __restrict__ W2h, u16* __restrict__ W2l,
        const float* __restrict__ W3, u16* __restrict__ W3h, u16* __restrict__ W3l,
        const float* __restrict__ Wd, u16* __restrict__ WdTh, u16* __restrict__ WdTl,
        const float* __restrict__ Wc2, u16* __restrict__ Wc2Th, u16* __restrict__ Wc2Tl,
        const float* __restrict__ Wm1, u16* __restrict__ Wm1Th, u16* __restrict__ Wm1Tl,
        const float* __restrict__ Wm2, u16* __restrict__ Wm2Th, u16* __restrict__ Wm2Tl) {
    __shared__ __align__(16) char smem[35840];
    int t = threadIdx.x;
    int bb = blockIdx.x;

    if (bb < CELLB) {
        // ---- cell path: 64 rows x 128 cols, K=1000 padded 1024 in 128-chunks ----
        u16* Xh = (u16*)(smem + 0);
        u16* Xl = (u16*)(smem + 17920);
        int row0 = bb * 64;
        int wave = t >> 6, lane = t & 63, quad = lane >> 4, l15 = lane & 15;
        int half = wave >> 2, wq = wave & 3;
        f32x4 acc[2][2] = {{{0.f,0.f,0.f,0.f},{0.f,0.f,0.f,0.f}},
                           {{0.f,0.f,0.f,0.f},{0.f,0.f,0.f,0.f}}};
        for (int ko = 0; ko < 8; ko++) {
#pragma unroll
            for (int ii = 0; ii < 4; ii++) {
                int i = t + ii * 512;          // float4 slot
                int r = i >> 5, c4 = i & 31;
                int col = ko * 128 + c4 * 4;
                float4 v = {0.f, 0.f, 0.f, 0.f};
                if (col < 1000) v = *(const float4*)(cf + (size_t)(row0 + r) * 1000 + col);
                float vv[4] = {v.x, v.y, v.z, v.w};
                short4v hs, ls;
#pragma unroll
                for (int j = 0; j < 4; j++) {
                    u16 h, l; split2(vv[j], h, l);
                    hs[j] = (short)h; ls[j] = (short)l;
                }
                *(short4v*)(Xh + r * 140 + c4 * 4) = hs;
                *(short4v*)(Xl + r * 140 + c4 * 4) = ls;
            }
            __syncthreads();
#pragma unroll
            for (int kk = 0; kk < 4; kk++) {
                int klo = kk * 32 + quad * 8;
                short8 ah[2], al[2];
#pragma unroll
                for (int mi = 0; mi < 2; mi++) {
                    ah[mi] = ld8(&Xh[(half * 32 + mi * 16 + l15) * 140 + klo]);
                    al[mi] = ld8(&Xl[(half * 32 + mi * 16 + l15) * 140 + klo]);
                }
#pragma unroll
                for (int ni = 0; ni < 2; ni++) {
                    int col = wq * 32 + ni * 16 + l15;
                    size_t o = (size_t)col * 1024 + ko * 128 + kk * 32 + quad * 8;
                    short8 bh = *(const short8*)(Wc1h + o);
                    short8 bl = *(const short8*)(Wc1l + o);
                    PRIO1();
#pragma unroll
                    for (int mi = 0; mi < 2; mi++) {
                        acc[mi][ni] = MFMA(ah[mi], bh, acc[mi][ni]);
                        acc[mi][ni] = MFMA(al[mi], bh, acc[mi][ni]);
                        acc[mi][ni] = MFMA(ah[mi], bl, acc[mi][ni]);
                    }
                    PRIO0();
                }
            }
            __syncthreads();
        }
#pragma unroll
        for (int ni = 0; ni < 2; ni++) {
            int col = wq * 32 + ni * 16 + l15;
            float bv = bc1[col];
#pragma unroll
            for (int mi = 0; mi < 2; mi++)
#pragma unroll
                for (int rg = 0; rg < 4; rg++) {
                    int row = row0 + half * 32 + mi * 16 + quad * 4 + rg;
                    cell1[(size_t)row * 128 + col] = fmaxf(acc[mi][ni][rg] + bv, 0.f);
                }
        }
        return;
    }
    bb -= CELLB;

    if (bb < NCNT) {
        // ---- edge counting (random global atomics) ----
        int e = bb * 512 + t;
        if (e < E) {
            int s = ei[e], d = ei[E + e];
            int g = d / 30;
            int idx = g * 960 + (d - g * 30) * 32 + (s - g * 30);
            atomicAdd(&A32[idx >> 1], 1u << ((idx & 1) * 16));
        }
        return;
    }
    bb -= NCNT;

    // ---- remaining weight splits (81920 elems) ----
    int i = bb * 512 + t;
    const float* W; u16 *th, *tl; int K, F, Kp;
    if (i < 6144)        { W = W1;  th = W1h;  tl = W1l;  K = 78;   F = 64;  Kp = 96; }
    else if (i < 14336)  { i -= 6144;   W = W2;  th = W2h;  tl = W2l;  K = 64;   F = 128; Kp = 64; }
    else if (i < 47104)  { i -= 14336;  W = W3;  th = W3h;  tl = W3l;  K = 128;  F = 256; Kp = 128; }
    else if (i < 63488)  { i -= 47104;  W = Wd;  th = WdTh; tl = WdTl; K = 256;  F = 64;  Kp = 256; }
    else if (i < 71680)  { i -= 63488;  W = Wc2; th = Wc2Th; tl = Wc2Tl; K = 128; F = 64; Kp = 128; }
    else if (i < 79872)  { i -= 71680;  W = Wm1; th = Wm1Th; tl = Wm1Tl; K = 128; F = 64; Kp = 128; }
    else if (i < 81920)  { i -= 79872;  W = Wm2; th = Wm2Th; tl = Wm2Tl; K = 64;  F = 32; Kp = 64; }
    else return;
    int f = i / Kp, k = i - f * Kp;
    float v = (k < K) ? W[(size_t)k * F + f] : 0.f;
    u16 h, l; split2(v, h, l);
    th[i] = h; tl[i] = l;
}

// ---------------- D3: fused GCN node pipeline, one block per graph ----------------
__global__ __launch_bounds__(512, 8) void k_node(
    const float* __restrict__ x, const unsigned* __restrict__ A32,
    const u16* __restrict__ W1h, const u16* __restrict__ W1l,
    const u16* __restrict__ W2h, const u16* __restrict__ W2l,
    const u16* __restrict__ W3h, const u16* __restrict__ W3l,
    const float* __restrict__ b1, const float* __restrict__ b2,
    const float* __restrict__ b3, float* __restrict__ P) {
    __shared__ __align__(16) char smem[39936];
    int t = threadIdx.x;
    int g = blockIdx.x;
    int wave = t >> 6, lane = t & 63, quad = lane >> 4, l15 = lane & 15;

    u16* xh  = (u16*)(smem + 0);
    u16* xl  = (u16*)(smem + 6400);
    u16* h1h = (u16*)(smem + 0);
    u16* h1l = (u16*)(smem + 4352);
    u16* a3h = (u16*)(smem + 0);
    u16* a3l = (u16*)(smem + 8448);
    float* Afp = (float*)(smem + 16896);
    float* dv  = (float*)(smem + 20736);
    u16* t1h = (u16*)(smem + 16896);
    u16* t1l = (u16*)(smem + 21504);
    u16* h2h = (u16*)(smem + 16896);
    u16* h2l = (u16*)(smem + 26112);
    u16* Ah  = (u16*)(smem + 35328);
    u16* Al  = (u16*)(smem + 37632);

    // Ph1: zero x pads; stage x split; stage Afp; dv from global counts
    {
        for (int i = t; i < 860; i += 512) {
            uint* arr = (uint*)((i >= 430) ? (char*)xl : (char*)xh);
            int j = (i >= 430) ? i - 430 : i;
            int r, c32;
            if (j < 330) { r = j / 11; c32 = 39 + j % 11; }
            else { r = 30 + (j - 330) / 50; c32 = (j - 330) % 50; }
            arr[r * 50 + c32] = 0;
        }
        const float4* xg = (const float4*)(x + (size_t)g * 2340);
        for (int i = t; i < 585; i += 512) {
            float4 v = xg[i];
            int base = i * 4;
            float vv[4] = {v.x, v.y, v.z, v.w};
#pragma unroll
            for (int j = 0; j < 4; j++) {
                int idx = base + j;
                int r = idx / 78, c = idx - r * 78;
                u16 h, l; split2(vv[j], h, l);
                xh[r * 100 + c] = h; xl[r * 100 + c] = l;
            }
        }
        const unsigned* ac = A32 + (size_t)g * 480;
        for (int i = t; i < 480; i += 512) {
            unsigned w = ac[i];
            Afp[2 * i] = (float)(w & 0xFFFFu);
            Afp[2 * i + 1] = (float)(w >> 16);
        }
        if (t < 32) {
            float s = 1.f;
            if (t < 30) {
                const unsigned* rp = ac + t * 16;
                unsigned acc = 0;
#pragma unroll
                for (int j = 0; j < 16; j++) { unsigned w = rp[j]; acc += (w & 0xFFFFu) + (w >> 16); }
                s += (float)acc;
            }
            dv[t] = (t < 30) ? rsqrtf(s) : 0.f;
        }
    }
    __syncthreads();
    // Ph3: A = (cnt + I) * dv_d * dv_s -> Ah/Al
    {
#pragma unroll
        for (int ii = 0; ii < 2; ii++) {
            int i = t + ii * 512;
            int r = i >> 5, c = i & 31;
            float a = 0.f;
            if (r < 30 && c < 30)
                a = (Afp[r * 32 + c] + (r == c ? 1.f : 0.f)) * dv[r] * dv[c];
            u16 h, l; split2(a, h, l);
            Ah[r * 36 + c] = h; Al[r * 36 + c] = l;
        }
    }
    __syncthreads();
    // Ph4: GEMM1  t1 = x @ W1  (M=32, N=64, K=96) -> t1T
    {
        int wm = wave >> 2, wn = wave & 3;
        int arow = wm * 16 + l15;
        int col = wn * 16 + l15;
        const u16* wph = W1h + col * 96 + quad * 8;
        const u16* wpl = W1l + col * 96 + quad * 8;
        f32x4 acc = {0.f, 0.f, 0.f, 0.f};
#pragma unroll
        for (int ch = 0; ch < 3; ch++) {
            int kc = ch * 32;
            short8 bh = *(const short8*)(wph + kc);
            short8 bl = *(const short8*)(wpl + kc);
            short8 ah = ld8(&xh[arow * 100 + kc + quad * 8]);
            short8 al = ld8(&xl[arow * 100 + kc + quad * 8]);
            PRIO1();
            acc = MFMA(ah, bh, acc);
            acc = MFMA(al, bh, acc);
            acc = MFMA(ah, bl, acc);
            PRIO0();
        }
#pragma unroll
        for (int rg = 0; rg < 4; rg++) {
            int row = wm * 16 + quad * 4 + rg;
            u16 h, l; split2(acc[rg], h, l);
            t1h[col * 36 + row] = h;
            t1l[col * 36 + row] = l;
        }
    }
    __syncthreads();
    // Ph5: agg1  h1 = relu(A @ t1 + b1)  (M=32, N=64, K=32)
    {
        int wm = wave >> 2, wn = wave & 3;
        int arow = wm * 16 + l15;
        int col = wn * 16 + l15;
        short8 aAh = ld8(&Ah[arow * 36 + quad * 8]);
        short8 aAl = ld8(&Al[arow * 36 + quad * 8]);
        short8 bh = ld8(&t1h[col * 36 + quad * 8]);
        short8 bl = ld8(&t1l[col * 36 + quad * 8]);
        f32x4 acc = {0.f, 0.f, 0.f, 0.f};
        PRIO1();
        acc = MFMA(aAh, bh, acc);
        acc = MFMA(aAl, bh, acc);
        acc = MFMA(aAh, bl, acc);
        PRIO0();
        float bb = b1[col];
#pragma unroll
        for (int rg = 0; rg < 4; rg++) {
            int row = wm * 16 + quad * 4 + rg;
            float v = fmaxf(acc[rg] + bb, 0.f);
            u16 h, l; split2(v, h, l);
            h1h[row * 68 + col] = h;
            h1l[row * 68 + col] = l;
        }
    }
    __syncthreads();
    // Ph6: GEMM2  h2 = relu(h1 @ W2 + b2)  (M=32, N=128, K=64) -> h2T
    {
        int col = wave * 16 + l15;
        const u16* wph = W2h + col * 64 + quad * 8;
        const u16* wpl = W2l + col * 64 + quad * 8;
        f32x4 acc[2] = {{0.f,0.f,0.f,0.f},{0.f,0.f,0.f,0.f}};
#pragma unroll
        for (int ch = 0; ch < 2; ch++) {
            int kc = ch * 32;
            short8 bh = *(const short8*)(wph + kc);
            short8 bl = *(const short8*)(wpl + kc);
#pragma unroll
            for (int mi = 0; mi < 2; mi++) {
                short8 ah = ld8(&h1h[(mi * 16 + l15) * 68 + kc + quad * 8]);
                short8 al = ld8(&h1l[(mi * 16 + l15) * 68 + kc + quad * 8]);
                PRIO1();
                acc[mi] = MFMA(ah, bh, acc[mi]);
                acc[mi] = MFMA(al, bh, acc[mi]);
                acc[mi] = MFMA(ah, bl, acc[mi]);
                PRIO0();
            }
        }
        float bb = b2[col];
#pragma unroll
        for (int mi = 0; mi < 2; mi++)
#pragma unroll
            for (int rg = 0; rg < 4; rg++) {
                int row = mi * 16 + quad * 4 + rg;
                float v = fmaxf(acc[mi][rg] + bb, 0.f);
                u16 h, l; split2(v, h, l);
                h2h[col * 36 + row] = h;
                h2l[col * 36 + row] = l;
            }
    }
    __syncthreads();
    // Ph7: agg2  a3 = A @ h2  (M=32, N=128, K=32)
    {
        int col = wave * 16 + l15;
        short8 bh = ld8(&h2h[col * 36 + quad * 8]);
        short8 bl = ld8(&h2l[col * 36 + quad * 8]);
        f32x4 acc[2] = {{0.f,0.f,0.f,0.f},{0.f,0.f,0.f,0.f}};
#pragma unroll
        for (int mi = 0; mi < 2; mi++) {
            short8 aAh = ld8(&Ah[(mi * 16 + l15) * 36 + quad * 8]);
            short8 aAl = ld8(&Al[(mi * 16 + l15) * 36 + quad * 8]);
            PRIO1();
            acc[mi] = MFMA(aAh, bh, acc[mi]);
            acc[mi] = MFMA(aAl, bh, acc[mi]);
            acc[mi] = MFMA(aAh, bl, acc[mi]);
            PRIO0();
        }
#pragma unroll
        for (int mi = 0; mi < 2; mi++)
#pragma unroll
            for (int rg = 0; rg < 4; rg++) {
                int row = mi * 16 + quad * 4 + rg;
                u16 h, l; split2(acc[mi][rg], h, l);
                a3h[row * 132 + col] = h;
                a3l[row * 132 + col] = l;
            }
    }
    __syncthreads();
    // Ph8: GEMM3 + pool (M=32, N=256, K=128)
    {
        int colb = wave * 32;
        f32x4 acc[2][2] = {{{0.f,0.f,0.f,0.f},{0.f,0.f,0.f,0.f}},
                           {{0.f,0.f,0.f,0.f},{0.f,0.f,0.f,0.f}}};
        short8 cwh[2], cwl[2], nwh[2], nwl[2];
#pragma unroll
        for (int ni = 0; ni < 2; ni++) {
            size_t o = (size_t)(colb + ni * 16 + l15) * 128 + quad * 8;
            cwh[ni] = *(const short8*)(W3h + o);
            cwl[ni] = *(const short8*)(W3l + o);
        }
#pragma unroll
        for (int ch = 0; ch < 4; ch++) {
            if (ch < 3) {
#pragma unroll
                for (int ni = 0; ni < 2; ni++) {
                    size_t o = (size_t)(colb + ni * 16 + l15) * 128 + (ch + 1) * 32 + quad * 8;
                    nwh[ni] = *(const short8*)(W3h + o);
                    nwl[ni] = *(const short8*)(W3l + o);
                }
            }
            short8 ah[2], al[2];
#pragma unroll
            for (int mi = 0; mi < 2; mi++) {
                ah[mi] = ld8(&a3h[(mi * 16 + l15) * 132 + ch * 32 + quad * 8]);
                al[mi] = ld8(&a3l[(mi * 16 + l15) * 132 + ch * 32 + quad * 8]);
            }
            PRIO1();
#pragma unroll
            for (int mi = 0; mi < 2; mi++)
#pragma unroll
                for (int ni = 0; ni < 2; ni++) {
                    acc[mi][ni] = MFMA(ah[mi], cwh[ni], acc[mi][ni]);
                    acc[mi][ni] = MFMA(al[mi], cwh[ni], acc[mi][ni]);
                    acc[mi][ni] = MFMA(ah[mi], cwl[ni], acc[mi][ni]);
                }
            PRIO0();
            if (ch < 3) {
#pragma unroll
                for (int ni = 0; ni < 2; ni++) { cwh[ni] = nwh[ni]; cwl[ni] = nwl[ni]; }
            }
        }
#pragma unroll
        for (int ni = 0; ni < 2; ni++) {
            int col = colb + ni * 16 + l15;
            float bb = b3[col];
            float p = 0.f;
#pragma unroll
            for (int mi = 0; mi < 2; mi++)
#pragma unroll
                for (int rg = 0; rg < 4; rg++) {
                    int row = mi * 16 + quad * 4 + rg;
                    if (row < 30) p += fmaxf(acc[mi][ni][rg] + bb, 0.f);
                }
            p += __shfl_down(p, 32);
            p += __shfl_down(p, 16);
            if (lane < 16)
                P[(size_t)g * 256 + colb + ni * 16 + lane] = p * (1.0f / 30.0f);
        }
    }
}

// ---------------- D4: MFMA tail: drug embed + cell2 + combiner head, 32 graphs/block ----
__global__ __launch_bounds__(256) void k_tail2(const float* __restrict__ pooled,
        const float* __restrict__ cell1,
        const u16* __restrict__ WdTh, const u16* __restrict__ WdTl, const float* __restrict__ bd,
        const u16* __restrict__ Wc2Th, const u16* __restrict__ Wc2Tl, const float* __restrict__ bc2,
        const u16* __restrict__ Wm1Th, const u16* __restrict__ Wm1Tl, const float* __restrict__ bm1,
        const u16* __restrict__ Wm2Th, const u16* __restrict__ Wm2Tl, const float* __restrict__ bm2,
        const float* __restrict__ Wo, const float* __restrict__ bo,
        float* __restrict__ out) {
    __shared__ __align__(16) char smem[50176];
    u16* Xh  = (u16*)(smem);
    u16* Xl  = (u16*)(smem + 25088);
    u16* dzh = (u16*)(smem);
    u16* dzl = (u16*)(smem + 8960);
    u16* z1h = (u16*)(smem + 17920);
    u16* z1l = (u16*)(smem + 22528);
    float* z2f = (float*)(smem + 27136);
    int t = threadIdx.x;
    int row0 = blockIdx.x * 32;
    int wave = t >> 6, lane = t & 63, quad = lane >> 4, l15 = lane & 15;

    // stage X = [pooled | cell1] split (32 rows x 96 float4)
#pragma unroll
    for (int ii = 0; ii < 12; ii++) {
        int i = t + ii * 256;
        int r = i / 96, c4 = i - r * 96;
        float4 v = (c4 < 64)
            ? ((const float4*)(pooled + (size_t)(row0 + r) * 256))[c4]
            : ((const float4*)(cell1 + (size_t)(row0 + r) * 128))[c4 - 64];
        float vv[4] = {v.x, v.y, v.z, v.w};
        short4v hs, ls;
#pragma unroll
        for (int j = 0; j < 4; j++) {
            u16 h, l; split2(vv[j], h, l);
            hs[j] = (short)h; ls[j] = (short)l;
        }
        *(short4v*)(Xh + r * 392 + c4 * 4) = hs;
        *(short4v*)(Xl + r * 392 + c4 * 4) = ls;
    }
    __syncthreads();

    // G1: waves 0,1 -> drug (K=256); waves 2,3 -> cellz (K=128)
    bool cw = wave >= 2;
    int nbase = (wave & 1) * 32;
    const u16* Bh = cw ? Wc2Th : WdTh;
    const u16* Bl = cw ? Wc2Tl : WdTl;
    const int Kp = cw ? 128 : 256;
    const int nch = cw ? 4 : 8;
    const int acol = cw ? 256 : 0;
    f32x4 acc[2][2] = {{{0.f,0.f,0.f,0.f},{0.f,0.f,0.f,0.f}},
                       {{0.f,0.f,0.f,0.f},{0.f,0.f,0.f,0.f}}};
    for (int ch = 0; ch < nch; ch++) {
        int kc = ch * 32 + quad * 8;
        short8 ah[2], al[2];
#pragma unroll
        for (int mi = 0; mi < 2; mi++) {
            ah[mi] = ld8(&Xh[(mi * 16 + l15) * 392 + acol + kc]);
            al[mi] = ld8(&Xl[(mi * 16 + l15) * 392 + acol + kc]);
        }
#pragma unroll
        for (int ni = 0; ni < 2; ni++) {
            int col = nbase + ni * 16 + l15;
            short8 bh = *(const short8*)(Bh + (size_t)col * Kp + kc);
            short8 bl = *(const short8*)(Bl + (size_t)col * Kp + kc);
#pragma unroll
            for (int mi = 0; mi < 2; mi++) {
                acc[mi][ni] = MFMA(ah[mi], bh, acc[mi][ni]);
                acc[mi][ni] = MFMA(al[mi], bh, acc[mi][ni]);
                acc[mi][ni] = MFMA(ah[mi], bl, acc[mi][ni]);
            }
        }
    }
    __syncthreads();
#pragma unroll
    for (int ni = 0; ni < 2; ni++) {
        int c = nbase + ni * 16 + l15;
        float bb = cw ? bc2[c] : bd[c];
        int col = (cw ? 64 : 0) + c;
#pragma unroll
        for (int mi = 0; mi < 2; mi++)
#pragma unroll
            for (int rg = 0; rg < 4; rg++) {
                int row = mi * 16 + quad * 4 + rg;
                u16 h, l; split2(acc[mi][ni][rg] + bb, h, l);
                dzh[row * 140 + col] = h;
                dzl[row * 140 + col] = l;
            }
    }
    __syncthreads();

    // G2: z1 = relu(dz @ Wm1T + bm1)  (M=32, N=64, K=128)
    {
        int col = wave * 16 + l15;
        f32x4 a2[2] = {{0.f,0.f,0.f,0.f},{0.f,0.f,0.f,0.f}};
#pragma unroll
        for (int ch = 0; ch < 4; ch++) {
            int kc = ch * 32 + quad * 8;
            short8 bh = *(const short8*)(Wm1Th + (size_t)col * 128 + kc);
            short8 bl = *(const short8*)(Wm1Tl + (size_t)col * 128 + kc);
#pragma unroll
            for (int mi = 0; mi < 2; mi++) {
                short8 ah = ld8(&dzh[(mi * 16 + l15) * 140 + kc]);
                short8 al = ld8(&dzl[(mi * 16 + l15) * 140 + kc]);
                a2[mi] = MFMA(ah, bh, a2[mi]);
                a2[mi] = MFMA(al, bh, a2[mi]);
                a2[mi] = MFMA(ah, bl, a2[mi]);
            }
        }
        float bb = bm1[col];
#pragma unroll
        for (int mi = 0; mi < 2; mi++)
#pragma unroll
            for (int rg = 0; rg < 4; rg++) {
                int row = mi * 16 + quad * 4 + rg;
                u16 h, l; split2(fmaxf(a2[mi][rg] + bb, 0.f), h, l);
                z1h[row * 72 + col] = h;
                z1l[row * 72 + col] = l;
            }
    }
    __syncthreads();

    // G3: z2 = relu(z1 @ Wm2T + bm2)  (M=32, N=32, K=64); waves 0,1
    if (wave < 2) {
        int col = wave * 16 + l15;
        f32x4 a3[2] = {{0.f,0.f,0.f,0.f},{0.f,0.f,0.f,0.f}};
#pragma unroll
        for (int ch = 0; ch < 2; ch++) {
            int kc = ch * 32 + quad * 8;
            short8 bh = *(const short8*)(Wm2Th + (size_t)col * 64 + kc);
            short8 bl = *(const short8*)(Wm2Tl + (size_t)col * 64 + kc);
#pragma unroll
            for (int mi = 0; mi < 2; mi++) {
                short8 ah = ld8(&z1h[(mi * 16 + l15) * 72 + kc]);
                short8 al = ld8(&z1l[(mi * 16 + l15) * 72 + kc]);
                a3[mi] = MFMA(ah, bh, a3[mi]);
                a3[mi] = MFMA(al, bh, a3[mi]);
                a3[mi] = MFMA(ah, bl, a3[mi]);
            }
        }
        float bb = bm2[col];
#pragma unroll
        for (int mi = 0; mi < 2; mi++)
#pragma unroll
            for (int rg = 0; rg < 4; rg++) {
                int row = mi * 16 + quad * 4 + rg;
                z2f[row * 33 + col] = fmaxf(a3[mi][rg] + bb, 0.f);
            }
    }
    __syncthreads();

    // G4: out = z2 . Wo + bo (fp32)
    if (t < 32) {
        float s = bo[0];
#pragma unroll 8
        for (int k = 0; k < 32; k++) s += z2f[t * 33 + k] * Wo[k];
        out[row0 + t] = s;
    }
}

// ---------------- launch ----------------

extern "C" void kernel_launch(void* const* d_in, const int* in_sizes, int n_in,
                              void* d_out, int out_size, void* d_ws, size_t ws_size,
                              hipStream_t stream) {
    const float* x   = (const float*)d_in[0];
    const int*   ei  = (const int*)d_in[1];
    const float* cf  = (const float*)d_in[3];
    const float* W1  = (const float*)d_in[4];
    const float* b1  = (const float*)d_in[5];
    const float* W2  = (const float*)d_in[6];
    const float* b2  = (const float*)d_in[7];
    const float* W3  = (const float*)d_in[8];
    const float* b3  = (const float*)d_in[9];
    const float* Wd  = (const float*)d_in[10];
    const float* bd  = (const float*)d_in[11];
    const float* Wc1 = (const float*)d_in[12];
    const float* bc1 = (const float*)d_in[13];
    const float* Wc2 = (const float*)d_in[14];
    const float* bc2 = (const float*)d_in[15];
    const float* Wm1 = (const float*)d_in[16];
    const float* bm1 = (const float*)d_in[17];
    const float* Wm2 = (const float*)d_in[18];
    const float* bm2 = (const float*)d_in[19];
    const float* Wo  = (const float*)d_in[20];
    const float* bo  = (const float*)d_in[21];
    float* out = (float*)d_out;

    const int E = in_sizes[1] / 2;     // 1,000,000
    const int B = in_sizes[3] / 1000;  // 8192

    char* w = (char*)d_ws;
    auto carve = [&](size_t bytes) { void* p = (void*)w; w += (bytes + 255) & ~(size_t)255; return p; };
    unsigned* A32 = (unsigned*)carve((size_t)B * 960 * 2);   // u16 counts, 15.7 MB
    float* pooled = (float*)carve((size_t)B * 256 * 4);
    float* cell1  = (float*)carve((size_t)B * 128 * 4);
    u16* W1th = (u16*)carve(64 * 96 * 2);     u16* W1tl = (u16*)carve(64 * 96 * 2);
    u16* W2th = (u16*)carve(128 * 64 * 2);    u16* W2tl = (u16*)carve(128 * 64 * 2);
    u16* W3th = (u16*)carve(256 * 128 * 2);   u16* W3tl = (u16*)carve(256 * 128 * 2);
    u16* Wc1th = (u16*)carve(128 * 1024 * 2); u16* Wc1tl = (u16*)carve(128 * 1024 * 2);
    u16* WdTh = (u16*)carve(64 * 256 * 2);    u16* WdTl = (u16*)carve(64 * 256 * 2);
    u16* Wc2Th = (u16*)carve(64 * 128 * 2);   u16* Wc2Tl = (u16*)carve(64 * 128 * 2);
    u16* Wm1Th = (u16*)carve(64 * 128 * 2);   u16* Wm1Tl = (u16*)carve(64 * 128 * 2);
    u16* Wm2Th = (u16*)carve(32 * 64 * 2);    u16* Wm2Tl = (u16*)carve(32 * 64 * 2);

    const int nz4 = B * 120;               // int4 slots to zero (15.7 MB)

    // D1: zero adjacency + Wc1 split (dependency of D2's cell blocks)
    k_pre<<<(nz4 + 131072 + 255) / 256, 256, 0, stream>>>((int4*)A32, nz4, Wc1, Wc1th, Wc1tl);

    // D2: cell1 GEMM + edge-count atomics + remaining weight splits, one dispatch
    const int CELLB = B / 64;              // 128 blocks x 64 rows
    const int NCNT = (E + 511) / 512;      // 1954 blocks
    const int NSPL = (81920 + 511) / 512;  // 160 blocks
    k_mix<<<CELLB + NCNT + NSPL, 512, 0, stream>>>(
        ei, A32, E, NCNT,
        cf, Wc1th, Wc1tl, bc1, cell1, CELLB,
        W1, W1th, W1tl, W2, W2th, W2tl, W3, W3th, W3tl,
        Wd, WdTh, WdTl, Wc2, Wc2Th, Wc2Tl, Wm1, Wm1Th, Wm1Tl, Wm2, Wm2Th, Wm2Tl);

    // D3: GCN node pipeline
    k_node<<<B, 512, 0, stream>>>(x, A32,
                                  W1th, W1tl, W2th, W2tl, W3th, W3tl,
                                  b1, b2, b3, pooled);

    // D4: MFMA tail
    k_tail2<<<B / 32, 256, 0, stream>>>(pooled, cell1,
                                        WdTh, WdTl, bd, Wc2Th, Wc2Tl, bc2,
                                        Wm1Th, Wm1Tl, bm1, Wm2Th, Wm2Tl, bm2,
                                        Wo, bo, out);
}

// Round 7
// 436.244 us; speedup vs baseline: 1.1508x; 1.1508x over previous
//
#include <hip/hip_runtime.h>

typedef __attribute__((ext_vector_type(8))) short short8;
typedef __attribute__((ext_vector_type(4))) short short4v;
typedef __attribute__((ext_vector_type(4))) float f32x4;
typedef unsigned short u16;

__device__ __forceinline__ u16 f2bf(float f) {
    union { float f; unsigned u; } v; v.f = f;
    unsigned r = v.u + 0x7FFFu + ((v.u >> 16) & 1u);
    return (u16)(r >> 16);
}
__device__ __forceinline__ float bf2f(u16 h) {
    union { unsigned u; float f; } v; v.u = ((unsigned)h) << 16;
    return v.f;
}
__device__ __forceinline__ void split2(float f, u16& h, u16& l) {
    h = f2bf(f);
    l = f2bf(f - bf2f(h));
}
// 8-byte-aligned LDS frag load
__device__ __forceinline__ short8 ld8(const u16* p) {
    short4v a = *(const short4v*)p;
    short4v b = *(const short4v*)(p + 4);
    short8 r;
    r[0] = a[0]; r[1] = a[1]; r[2] = a[2]; r[3] = a[3];
    r[4] = b[0]; r[5] = b[1]; r[6] = b[2]; r[7] = b[3];
    return r;
}
#define MFMA(A, B, C) __builtin_amdgcn_mfma_f32_16x16x32_bf16(A, B, C, 0, 0, 0)

// ---------------- merged prep: zero A32 + all 8 weight splits ----------------
__global__ __launch_bounds__(256) void k_prep(int4* __restrict__ A32z, int nz4,
        const float* __restrict__ W1, u16* __restrict__ W1h, u16* __restrict__ W1l,
        const float* __restrict__ W2, u16* __restrict__ W2h, u16* __restrict__ W2l,
        const float* __restrict__ W3, u16* __restrict__ W3h, u16* __restrict__ W3l,
        const float* __restrict__ Wc1, u16* __restrict__ Wc1h, u16* __restrict__ Wc1l,
        const float* __restrict__ Wd, u16* __restrict__ WdTh, u16* __restrict__ WdTl,
        const float* __restrict__ Wc2, u16* __restrict__ Wc2Th, u16* __restrict__ Wc2Tl,
        const float* __restrict__ Wm1, u16* __restrict__ Wm1Th, u16* __restrict__ Wm1Tl,
        const float* __restrict__ Wm2, u16* __restrict__ Wm2Th, u16* __restrict__ Wm2Tl) {
    int i = blockIdx.x * 256 + threadIdx.x;
    if (i < nz4) { A32z[i] = make_int4(0, 0, 0, 0); return; }
    i -= nz4;
    const float* W; u16 *th, *tl; int K, F, Kp;
    if (i < 6144)        { W = W1;  th = W1h;  tl = W1l;  K = 78;   F = 64;  Kp = 96; }
    else if (i < 14336)  { i -= 6144;   W = W2;  th = W2h;  tl = W2l;  K = 64;   F = 128; Kp = 64; }
    else if (i < 47104)  { i -= 14336;  W = W3;  th = W3h;  tl = W3l;  K = 128;  F = 256; Kp = 128; }
    else if (i < 178176) { i -= 47104;  W = Wc1; th = Wc1h; tl = Wc1l; K = 1000; F = 128; Kp = 1024; }
    else if (i < 194560) { i -= 178176; W = Wd;  th = WdTh; tl = WdTl; K = 256;  F = 64;  Kp = 256; }
    else if (i < 202752) { i -= 194560; W = Wc2; th = Wc2Th; tl = Wc2Tl; K = 128; F = 64; Kp = 128; }
    else if (i < 210944) { i -= 202752; W = Wm1; th = Wm1Th; tl = Wm1Tl; K = 128; F = 64; Kp = 128; }
    else if (i < 212992) { i -= 210944; W = Wm2; th = Wm2Th; tl = Wm2Tl; K = 64;  F = 32; Kp = 64; }
    else return;
    int f = i / Kp, k = i - f * Kp;
    float v = (k < K) ? W[(size_t)k * F + f] : 0.f;
    u16 h, l; split2(v, h, l);
    th[i] = h; tl[i] = l;
}

// per-graph 30x32 adjacency count matrix, u16 packed in u32 pairs (random global atomics)
__global__ void k_cnt(const int* __restrict__ ei, unsigned* __restrict__ A32, int E) {
    int e = blockIdx.x * 256 + threadIdx.x;
    if (e >= E) return;
    int s = ei[e], d = ei[E + e];
    int g = d / 30;
    int idx = g * 960 + (d - g * 30) * 32 + (s - g * 30);
    atomicAdd(&A32[idx >> 1], 1u << ((idx & 1) * 16));
}

// ---------------- fused node pipeline + cell1 GEMM, 2 graphs (or 128 cell rows) per block ----
// 1024 threads; half-block hb = t>>9 runs the verified 512-thread body on its own LDS slice.
// blocks [0, CELLB): cell1 = relu(cf @ Wc1 + bc1), 128 rows/block (64 per half)
// blocks [CELLB, CELLB+B/2): GCN node pipeline, graphs 2*b+hb
__global__ __launch_bounds__(1024, 8) void k_nodecell(
    const float* __restrict__ x, const unsigned* __restrict__ A32,
    const u16* __restrict__ W1h, const u16* __restrict__ W1l,
    const u16* __restrict__ W2h, const u16* __restrict__ W2l,
    const u16* __restrict__ W3h, const u16* __restrict__ W3l,
    const float* __restrict__ b1, const float* __restrict__ b2,
    const float* __restrict__ b3, float* __restrict__ P,
    const float* __restrict__ cf,
    const u16* __restrict__ Wc1h, const u16* __restrict__ Wc1l,
    const float* __restrict__ bc1, float* __restrict__ cell1,
    int CELLB) {
    __shared__ __align__(16) char smem_all[79872];
    int t = threadIdx.x;
    int hb = t >> 9;          // half-block id
    int tl = t & 511;         // thread id within half
    int wave = tl >> 6, lane = tl & 63, quad = lane >> 4, l15 = lane & 15;

    if (blockIdx.x < CELLB) {
        // ---- cell path: 64 rows x 128 cols per half, K=1000 padded 1024 in 128-chunks ----
        char* smem = smem_all + hb * 35840;
        u16* Xh = (u16*)(smem + 0);
        u16* Xl = (u16*)(smem + 17920);
        int row0 = blockIdx.x * 128 + hb * 64;
        int whf = wave >> 2, wq = wave & 3;
        f32x4 acc[2][2] = {{{0.f,0.f,0.f,0.f},{0.f,0.f,0.f,0.f}},
                           {{0.f,0.f,0.f,0.f},{0.f,0.f,0.f,0.f}}};
        for (int ko = 0; ko < 8; ko++) {
#pragma unroll
            for (int ii = 0; ii < 4; ii++) {
                int i = tl + ii * 512;          // float4 slot
                int r = i >> 5, c4 = i & 31;
                int col = ko * 128 + c4 * 4;
                float4 v = {0.f, 0.f, 0.f, 0.f};
                if (col < 1000) v = *(const float4*)(cf + (size_t)(row0 + r) * 1000 + col);
                float vv[4] = {v.x, v.y, v.z, v.w};
                short4v hs, ls;
#pragma unroll
                for (int j = 0; j < 4; j++) {
                    u16 h, l; split2(vv[j], h, l);
                    hs[j] = (short)h; ls[j] = (short)l;
                }
                *(short4v*)(Xh + r * 140 + c4 * 4) = hs;
                *(short4v*)(Xl + r * 140 + c4 * 4) = ls;
            }
            __syncthreads();
#pragma unroll
            for (int kk = 0; kk < 4; kk++) {
                int klo = kk * 32 + quad * 8;
                short8 ah[2], al[2];
#pragma unroll
                for (int mi = 0; mi < 2; mi++) {
                    ah[mi] = ld8(&Xh[(whf * 32 + mi * 16 + l15) * 140 + klo]);
                    al[mi] = ld8(&Xl[(whf * 32 + mi * 16 + l15) * 140 + klo]);
                }
#pragma unroll
                for (int ni = 0; ni < 2; ni++) {
                    int col = wq * 32 + ni * 16 + l15;
                    size_t o = (size_t)col * 1024 + ko * 128 + kk * 32 + quad * 8;
                    short8 bh = *(const short8*)(Wc1h + o);
                    short8 bl = *(const short8*)(Wc1l + o);
#pragma unroll
                    for (int mi = 0; mi < 2; mi++) {
                        acc[mi][ni] = MFMA(ah[mi], bh, acc[mi][ni]);
                        acc[mi][ni] = MFMA(al[mi], bh, acc[mi][ni]);
                        acc[mi][ni] = MFMA(ah[mi], bl, acc[mi][ni]);
                    }
                }
            }
            __syncthreads();
        }
#pragma unroll
        for (int ni = 0; ni < 2; ni++) {
            int col = wq * 32 + ni * 16 + l15;
            float bv = bc1[col];
#pragma unroll
            for (int mi = 0; mi < 2; mi++)
#pragma unroll
                for (int rg = 0; rg < 4; rg++) {
                    int row = row0 + whf * 32 + mi * 16 + quad * 4 + rg;
                    cell1[(size_t)row * 128 + col] = fmaxf(acc[mi][ni][rg] + bv, 0.f);
                }
        }
        return;
    }

    // ---- node path (verbatim verified body on tl; one graph per half-block) ----
    char* smem = smem_all + hb * 39936;
    int g = (blockIdx.x - CELLB) * 2 + hb;
    u16* xh  = (u16*)(smem + 0);
    u16* xl  = (u16*)(smem + 6400);
    u16* h1h = (u16*)(smem + 0);
    u16* h1l = (u16*)(smem + 4352);
    u16* a3h = (u16*)(smem + 0);
    u16* a3l = (u16*)(smem + 8448);
    float* Afp = (float*)(smem + 16896);
    float* dv  = (float*)(smem + 20736);
    u16* t1h = (u16*)(smem + 16896);
    u16* t1l = (u16*)(smem + 21504);
    u16* h2h = (u16*)(smem + 16896);
    u16* h2l = (u16*)(smem + 26112);
    u16* Ah  = (u16*)(smem + 35328);
    u16* Al  = (u16*)(smem + 37632);

    // Ph1: zero x pads; stage x split; stage Afp; dv from global counts
    {
        for (int i = tl; i < 860; i += 512) {
            uint* arr = (uint*)((i >= 430) ? (char*)xl : (char*)xh);
            int j = (i >= 430) ? i - 430 : i;
            int r, c32;
            if (j < 330) { r = j / 11; c32 = 39 + j % 11; }
            else { r = 30 + (j - 330) / 50; c32 = (j - 330) % 50; }
            arr[r * 50 + c32] = 0;
        }
        const float4* xg = (const float4*)(x + (size_t)g * 2340);
        for (int i = tl; i < 585; i += 512) {
            float4 v = xg[i];
            int base = i * 4;
            float vv[4] = {v.x, v.y, v.z, v.w};
#pragma unroll
            for (int j = 0; j < 4; j++) {
                int idx = base + j;
                int r = idx / 78, c = idx - r * 78;
                u16 h, l; split2(vv[j], h, l);
                xh[r * 100 + c] = h; xl[r * 100 + c] = l;
            }
        }
        const unsigned* ac = A32 + (size_t)g * 480;
        for (int i = tl; i < 480; i += 512) {
            unsigned w = ac[i];
            Afp[2 * i] = (float)(w & 0xFFFFu);
            Afp[2 * i + 1] = (float)(w >> 16);
        }
        if (tl < 32) {
            float s = 1.f;
            if (tl < 30) {
                const unsigned* rp = ac + tl * 16;
                unsigned acc = 0;
#pragma unroll
                for (int j = 0; j < 16; j++) { unsigned w = rp[j]; acc += (w & 0xFFFFu) + (w >> 16); }
                s += (float)acc;
            }
            dv[tl] = (tl < 30) ? rsqrtf(s) : 0.f;
        }
    }
    __syncthreads();
    // Ph3: A = (cnt + I) * dv_d * dv_s -> Ah/Al
    {
#pragma unroll
        for (int ii = 0; ii < 2; ii++) {
            int i = tl + ii * 512;
            int r = i >> 5, c = i & 31;
            float a = 0.f;
            if (r < 30 && c < 30)
                a = (Afp[r * 32 + c] + (r == c ? 1.f : 0.f)) * dv[r] * dv[c];
            u16 h, l; split2(a, h, l);
            Ah[r * 36 + c] = h; Al[r * 36 + c] = l;
        }
    }
    __syncthreads();
    // Ph4: GEMM1  t1 = x @ W1  (M=32, N=64, K=96) -> t1T
    {
        int wm = wave >> 2, wn = wave & 3;
        int arow = wm * 16 + l15;
        int col = wn * 16 + l15;
        const u16* wph = W1h + col * 96 + quad * 8;
        const u16* wpl = W1l + col * 96 + quad * 8;
        f32x4 acc = {0.f, 0.f, 0.f, 0.f};
#pragma unroll
        for (int ch = 0; ch < 3; ch++) {
            int kc = ch * 32;
            short8 bh = *(const short8*)(wph + kc);
            short8 bl = *(const short8*)(wpl + kc);
            short8 ah = ld8(&xh[arow * 100 + kc + quad * 8]);
            short8 al = ld8(&xl[arow * 100 + kc + quad * 8]);
            acc = MFMA(ah, bh, acc);
            acc = MFMA(al, bh, acc);
            acc = MFMA(ah, bl, acc);
        }
#pragma unroll
        for (int rg = 0; rg < 4; rg++) {
            int row = wm * 16 + quad * 4 + rg;
            u16 h, l; split2(acc[rg], h, l);
            t1h[col * 36 + row] = h;
            t1l[col * 36 + row] = l;
        }
    }
    __syncthreads();
    // Ph5: agg1  h1 = relu(A @ t1 + b1)  (M=32, N=64, K=32)
    {
        int wm = wave >> 2, wn = wave & 3;
        int arow = wm * 16 + l15;
        int col = wn * 16 + l15;
        short8 aAh = ld8(&Ah[arow * 36 + quad * 8]);
        short8 aAl = ld8(&Al[arow * 36 + quad * 8]);
        short8 bh = ld8(&t1h[col * 36 + quad * 8]);
        short8 bl = ld8(&t1l[col * 36 + quad * 8]);
        f32x4 acc = {0.f, 0.f, 0.f, 0.f};
        acc = MFMA(aAh, bh, acc);
        acc = MFMA(aAl, bh, acc);
        acc = MFMA(aAh, bl, acc);
        float bb = b1[col];
#pragma unroll
        for (int rg = 0; rg < 4; rg++) {
            int row = wm * 16 + quad * 4 + rg;
            float v = fmaxf(acc[rg] + bb, 0.f);
            u16 h, l; split2(v, h, l);
            h1h[row * 68 + col] = h;
            h1l[row * 68 + col] = l;
        }
    }
    __syncthreads();
    // Ph6: GEMM2  h2 = relu(h1 @ W2 + b2)  (M=32, N=128, K=64) -> h2T
    {
        int col = wave * 16 + l15;
        const u16* wph = W2h + col * 64 + quad * 8;
        const u16* wpl = W2l + col * 64 + quad * 8;
        f32x4 acc[2] = {{0.f,0.f,0.f,0.f},{0.f,0.f,0.f,0.f}};
#pragma unroll
        for (int ch = 0; ch < 2; ch++) {
            int kc = ch * 32;
            short8 bh = *(const short8*)(wph + kc);
            short8 bl = *(const short8*)(wpl + kc);
#pragma unroll
            for (int mi = 0; mi < 2; mi++) {
                short8 ah = ld8(&h1h[(mi * 16 + l15) * 68 + kc + quad * 8]);
                short8 al = ld8(&h1l[(mi * 16 + l15) * 68 + kc + quad * 8]);
                acc[mi] = MFMA(ah, bh, acc[mi]);
                acc[mi] = MFMA(al, bh, acc[mi]);
                acc[mi] = MFMA(ah, bl, acc[mi]);
            }
        }
        float bb = b2[col];
#pragma unroll
        for (int mi = 0; mi < 2; mi++)
#pragma unroll
            for (int rg = 0; rg < 4; rg++) {
                int row = mi * 16 + quad * 4 + rg;
                float v = fmaxf(acc[mi][rg] + bb, 0.f);
                u16 h, l; split2(v, h, l);
                h2h[col * 36 + row] = h;
                h2l[col * 36 + row] = l;
            }
    }
    __syncthreads();
    // Ph7: agg2  a3 = A @ h2  (M=32, N=128, K=32)
    {
        int col = wave * 16 + l15;
        short8 bh = ld8(&h2h[col * 36 + quad * 8]);
        short8 bl = ld8(&h2l[col * 36 + quad * 8]);
        f32x4 acc[2] = {{0.f,0.f,0.f,0.f},{0.f,0.f,0.f,0.f}};
#pragma unroll
        for (int mi = 0; mi < 2; mi++) {
            short8 aAh = ld8(&Ah[(mi * 16 + l15) * 36 + quad * 8]);
            short8 aAl = ld8(&Al[(mi * 16 + l15) * 36 + quad * 8]);
            acc[mi] = MFMA(aAh, bh, acc[mi]);
            acc[mi] = MFMA(aAl, bh, acc[mi]);
            acc[mi] = MFMA(aAh, bl, acc[mi]);
        }
#pragma unroll
        for (int mi = 0; mi < 2; mi++)
#pragma unroll
            for (int rg = 0; rg < 4; rg++) {
                int row = mi * 16 + quad * 4 + rg;
                u16 h, l; split2(acc[mi][rg], h, l);
                a3h[row * 132 + col] = h;
                a3l[row * 132 + col] = l;
            }
    }
    __syncthreads();
    // Ph8: GEMM3 + pool (M=32, N=256, K=128)
    {
        int colb = wave * 32;
        f32x4 acc[2][2] = {{{0.f,0.f,0.f,0.f},{0.f,0.f,0.f,0.f}},
                           {{0.f,0.f,0.f,0.f},{0.f,0.f,0.f,0.f}}};
        short8 cwh[2], cwl[2], nwh[2], nwl[2];
#pragma unroll
        for (int ni = 0; ni < 2; ni++) {
            size_t o = (size_t)(colb + ni * 16 + l15) * 128 + quad * 8;
            cwh[ni] = *(const short8*)(W3h + o);
            cwl[ni] = *(const short8*)(W3l + o);
        }
#pragma unroll
        for (int ch = 0; ch < 4; ch++) {
            if (ch < 3) {
#pragma unroll
                for (int ni = 0; ni < 2; ni++) {
                    size_t o = (size_t)(colb + ni * 16 + l15) * 128 + (ch + 1) * 32 + quad * 8;
                    nwh[ni] = *(const short8*)(W3h + o);
                    nwl[ni] = *(const short8*)(W3l + o);
                }
            }
            short8 ah[2], al[2];
#pragma unroll
            for (int mi = 0; mi < 2; mi++) {
                ah[mi] = ld8(&a3h[(mi * 16 + l15) * 132 + ch * 32 + quad * 8]);
                al[mi] = ld8(&a3l[(mi * 16 + l15) * 132 + ch * 32 + quad * 8]);
            }
#pragma unroll
            for (int mi = 0; mi < 2; mi++)
#pragma unroll
                for (int ni = 0; ni < 2; ni++) {
                    acc[mi][ni] = MFMA(ah[mi], cwh[ni], acc[mi][ni]);
                    acc[mi][ni] = MFMA(al[mi], cwh[ni], acc[mi][ni]);
                    acc[mi][ni] = MFMA(ah[mi], cwl[ni], acc[mi][ni]);
                }
            if (ch < 3) {
#pragma unroll
                for (int ni = 0; ni < 2; ni++) { cwh[ni] = nwh[ni]; cwl[ni] = nwl[ni]; }
            }
        }
#pragma unroll
        for (int ni = 0; ni < 2; ni++) {
            int col = colb + ni * 16 + l15;
            float bb = b3[col];
            float p = 0.f;
#pragma unroll
            for (int mi = 0; mi < 2; mi++)
#pragma unroll
                for (int rg = 0; rg < 4; rg++) {
                    int row = mi * 16 + quad * 4 + rg;
                    if (row < 30) p += fmaxf(acc[mi][ni][rg] + bb, 0.f);
                }
            p += __shfl_down(p, 32);
            p += __shfl_down(p, 16);
            if (lane < 16)
                P[(size_t)g * 256 + colb + ni * 16 + lane] = p * (1.0f / 30.0f);
        }
    }
}

// ---------------- MFMA tail: drug embed + cell2 + combiner head, 32 graphs/block ----------------
__global__ __launch_bounds__(256) void k_tail2(const float* __restrict__ pooled,
        const float* __restrict__ cell1,
        const u16* __restrict__ WdTh, const u16* __restrict__ WdTl, const float* __restrict__ bd,
        const u16* __restrict__ Wc2Th, const u16* __restrict__ Wc2Tl, const float* __restrict__ bc2,
        const u16* __restrict__ Wm1Th, const u16* __restrict__ Wm1Tl, const float* __restrict__ bm1,
        const u16* __restrict__ Wm2Th, const u16* __restrict__ Wm2Tl, const float* __restrict__ bm2,
        const float* __restrict__ Wo, const float* __restrict__ bo,
        float* __restrict__ out) {
    __shared__ __align__(16) char smem[50176];
    u16* Xh  = (u16*)(smem);
    u16* Xl  = (u16*)(smem + 25088);
    u16* dzh = (u16*)(smem);
    u16* dzl = (u16*)(smem + 8960);
    u16* z1h = (u16*)(smem + 17920);
    u16* z1l = (u16*)(smem + 22528);
    float* z2f = (float*)(smem + 27136);
    int t = threadIdx.x;
    int row0 = blockIdx.x * 32;
    int wave = t >> 6, lane = t & 63, quad = lane >> 4, l15 = lane & 15;

    // stage X = [pooled | cell1] split (32 rows x 96 float4)
#pragma unroll
    for (int ii = 0; ii < 12; ii++) {
        int i = t + ii * 256;
        int r = i / 96, c4 = i - r * 96;
        float4 v = (c4 < 64)
            ? ((const float4*)(pooled + (size_t)(row0 + r) * 256))[c4]
            : ((const float4*)(cell1 + (size_t)(row0 + r) * 128))[c4 - 64];
        float vv[4] = {v.x, v.y, v.z, v.w};
        short4v hs, ls;
#pragma unroll
        for (int j = 0; j < 4; j++) {
            u16 h, l; split2(vv[j], h, l);
            hs[j] = (short)h; ls[j] = (short)l;
        }
        *(short4v*)(Xh + r * 392 + c4 * 4) = hs;
        *(short4v*)(Xl + r * 392 + c4 * 4) = ls;
    }
    __syncthreads();

    // G1: waves 0,1 -> drug (K=256); waves 2,3 -> cellz (K=128)
    bool cw = wave >= 2;
    int nbase = (wave & 1) * 32;
    const u16* Bh = cw ? Wc2Th : WdTh;
    const u16* Bl = cw ? Wc2Tl : WdTl;
    const int Kp = cw ? 128 : 256;
    const int nch = cw ? 4 : 8;
    const int acol = cw ? 256 : 0;
    f32x4 acc[2][2] = {{{0.f,0.f,0.f,0.f},{0.f,0.f,0.f,0.f}},
                       {{0.f,0.f,0.f,0.f},{0.f,0.f,0.f,0.f}}};
    for (int ch = 0; ch < nch; ch++) {
        int kc = ch * 32 + quad * 8;
        short8 ah[2], al[2];
#pragma unroll
        for (int mi = 0; mi < 2; mi++) {
            ah[mi] = ld8(&Xh[(mi * 16 + l15) * 392 + acol + kc]);
            al[mi] = ld8(&Xl[(mi * 16 + l15) * 392 + acol + kc]);
        }
#pragma unroll
        for (int ni = 0; ni < 2; ni++) {
            int col = nbase + ni * 16 + l15;
            short8 bh = *(const short8*)(Bh + (size_t)col * Kp + kc);
            short8 bl = *(const short8*)(Bl + (size_t)col * Kp + kc);
#pragma unroll
            for (int mi = 0; mi < 2; mi++) {
                acc[mi][ni] = MFMA(ah[mi], bh, acc[mi][ni]);
                acc[mi][ni] = MFMA(al[mi], bh, acc[mi][ni]);
                acc[mi][ni] = MFMA(ah[mi], bl, acc[mi][ni]);
            }
        }
    }
    __syncthreads();
#pragma unroll
    for (int ni = 0; ni < 2; ni++) {
        int c = nbase + ni * 16 + l15;
        float bb = cw ? bc2[c] : bd[c];
        int col = (cw ? 64 : 0) + c;
#pragma unroll
        for (int mi = 0; mi < 2; mi++)
#pragma unroll
            for (int rg = 0; rg < 4; rg++) {
                int row = mi * 16 + quad * 4 + rg;
                u16 h, l; split2(acc[mi][ni][rg] + bb, h, l);
                dzh[row * 140 + col] = h;
                dzl[row * 140 + col] = l;
            }
    }
    __syncthreads();

    // G2: z1 = relu(dz @ Wm1T + bm1)  (M=32, N=64, K=128)
    {
        int col = wave * 16 + l15;
        f32x4 a2[2] = {{0.f,0.f,0.f,0.f},{0.f,0.f,0.f,0.f}};
#pragma unroll
        for (int ch = 0; ch < 4; ch++) {
            int kc = ch * 32 + quad * 8;
            short8 bh = *(const short8*)(Wm1Th + (size_t)col * 128 + kc);
            short8 bl = *(const short8*)(Wm1Tl + (size_t)col * 128 + kc);
#pragma unroll
            for (int mi = 0; mi < 2; mi++) {
                short8 ah = ld8(&dzh[(mi * 16 + l15) * 140 + kc]);
                short8 al = ld8(&dzl[(mi * 16 + l15) * 140 + kc]);
                a2[mi] = MFMA(ah, bh, a2[mi]);
                a2[mi] = MFMA(al, bh, a2[mi]);
                a2[mi] = MFMA(ah, bl, a2[mi]);
            }
        }
        float bb = bm1[col];
#pragma unroll
        for (int mi = 0; mi < 2; mi++)
#pragma unroll
            for (int rg = 0; rg < 4; rg++) {
                int row = mi * 16 + quad * 4 + rg;
                u16 h, l; split2(fmaxf(a2[mi][rg] + bb, 0.f), h, l);
                z1h[row * 72 + col] = h;
                z1l[row * 72 + col] = l;
            }
    }
    __syncthreads();

    // G3: z2 = relu(z1 @ Wm2T + bm2)  (M=32, N=32, K=64); waves 0,1
    if (wave < 2) {
        int col = wave * 16 + l15;
        f32x4 a3[2] = {{0.f,0.f,0.f,0.f},{0.f,0.f,0.f,0.f}};
#pragma unroll
        for (int ch = 0; ch < 2; ch++) {
            int kc = ch * 32 + quad * 8;
            short8 bh = *(const short8*)(Wm2Th + (size_t)col * 64 + kc);
            short8 bl = *(const short8*)(Wm2Tl + (size_t)col * 64 + kc);
#pragma unroll
            for (int mi = 0; mi < 2; mi++) {
                short8 ah = ld8(&z1h[(mi * 16 + l15) * 72 + kc]);
                short8 al = ld8(&z1l[(mi * 16 + l15) * 72 + kc]);
                a3[mi] = MFMA(ah, bh, a3[mi]);
                a3[mi] = MFMA(al, bh, a3[mi]);
                a3[mi] = MFMA(ah, bl, a3[mi]);
            }
        }
        float bb = bm2[col];
#pragma unroll
        for (int mi = 0; mi < 2; mi++)
#pragma unroll
            for (int rg = 0; rg < 4; rg++) {
                int row = mi * 16 + quad * 4 + rg;
                z2f[row * 33 + col] = fmaxf(a3[mi][rg] + bb, 0.f);
            }
    }
    __syncthreads();

    // G4: out = z2 . Wo + bo (fp32)
    if (t < 32) {
        float s = bo[0];
#pragma unroll 8
        for (int k = 0; k < 32; k++) s += z2f[t * 33 + k] * Wo[k];
        out[row0 + t] = s;
    }
}

// ---------------- launch ----------------

extern "C" void kernel_launch(void* const* d_in, const int* in_sizes, int n_in,
                              void* d_out, int out_size, void* d_ws, size_t ws_size,
                              hipStream_t stream) {
    const float* x   = (const float*)d_in[0];
    const int*   ei  = (const int*)d_in[1];
    const float* cf  = (const float*)d_in[3];
    const float* W1  = (const float*)d_in[4];
    const float* b1  = (const float*)d_in[5];
    const float* W2  = (const float*)d_in[6];
    const float* b2  = (const float*)d_in[7];
    const float* W3  = (const float*)d_in[8];
    const float* b3  = (const float*)d_in[9];
    const float* Wd  = (const float*)d_in[10];
    const float* bd  = (const float*)d_in[11];
    const float* Wc1 = (const float*)d_in[12];
    const float* bc1 = (const float*)d_in[13];
    const float* Wc2 = (const float*)d_in[14];
    const float* bc2 = (const float*)d_in[15];
    const float* Wm1 = (const float*)d_in[16];
    const float* bm1 = (const float*)d_in[17];
    const float* Wm2 = (const float*)d_in[18];
    const float* bm2 = (const float*)d_in[19];
    const float* Wo  = (const float*)d_in[20];
    const float* bo  = (const float*)d_in[21];
    float* out = (float*)d_out;

    const int E = in_sizes[1] / 2;     // 1,000,000
    const int B = in_sizes[3] / 1000;  // 8192

    char* w = (char*)d_ws;
    auto carve = [&](size_t bytes) { void* p = (void*)w; w += (bytes + 255) & ~(size_t)255; return p; };
    unsigned* A32 = (unsigned*)carve((size_t)B * 960 * 2);   // u16 counts, 15.7 MB
    float* pooled = (float*)carve((size_t)B * 256 * 4);
    float* cell1  = (float*)carve((size_t)B * 128 * 4);
    u16* W1th = (u16*)carve(64 * 96 * 2);     u16* W1tl = (u16*)carve(64 * 96 * 2);
    u16* W2th = (u16*)carve(128 * 64 * 2);    u16* W2tl = (u16*)carve(128 * 64 * 2);
    u16* W3th = (u16*)carve(256 * 128 * 2);   u16* W3tl = (u16*)carve(256 * 128 * 2);
    u16* Wc1th = (u16*)carve(128 * 1024 * 2); u16* Wc1tl = (u16*)carve(128 * 1024 * 2);
    u16* WdTh = (u16*)carve(64 * 256 * 2);    u16* WdTl = (u16*)carve(64 * 256 * 2);
    u16* Wc2Th = (u16*)carve(64 * 128 * 2);   u16* Wc2Tl = (u16*)carve(64 * 128 * 2);
    u16* Wm1Th = (u16*)carve(64 * 128 * 2);   u16* Wm1Tl = (u16*)carve(64 * 128 * 2);
    u16* Wm2Th = (u16*)carve(32 * 64 * 2);    u16* Wm2Tl = (u16*)carve(32 * 64 * 2);

    auto g1 = [](int n) { return (n + 255) / 256; };

    const int nz4 = B * 120;               // int4 slots to zero (15.7 MB)
    const int nsplit = 212992;

    // 1) merged prep: zero adjacency + all weight splits
    k_prep<<<g1(nz4 + nsplit), 256, 0, stream>>>((int4*)A32, nz4,
        W1, W1th, W1tl, W2, W2th, W2tl, W3, W3th, W3tl, Wc1, Wc1th, Wc1tl,
        Wd, WdTh, WdTl, Wc2, Wc2Th, Wc2Tl, Wm1, Wm1Th, Wm1Tl, Wm2, Wm2Th, Wm2Tl);

    // 2) edge counting (random global atomics — empirically the fastest variant)
    k_cnt<<<g1(E), 256, 0, stream>>>(ei, A32, E);

    // 3) fused GCN pipeline (2 graphs/block) + cell1 GEMM (128 rows/block), one dispatch
    const int CELLB = B / 128;             // 64 cell blocks
    k_nodecell<<<CELLB + B / 2, 1024, 0, stream>>>(x, A32,
                                  W1th, W1tl, W2th, W2tl, W3th, W3tl,
                                  b1, b2, b3, pooled,
                                  cf, Wc1th, Wc1tl, bc1, cell1, CELLB);

    // 4) MFMA tail: drug embed + cell2 + combiner head
    k_tail2<<<B / 32, 256, 0, stream>>>(pooled, cell1,
                                        WdTh, WdTl, bd, Wc2Th, Wc2Tl, bc2,
                                        Wm1Th, Wm1Tl, bm1, Wm2Th, Wm2Tl, bm2,
                                        Wo, bo, out);
}

// Round 8
// 413.108 us; speedup vs baseline: 1.2152x; 1.0560x over previous
//
#include <hip/hip_runtime.h>

typedef __attribute__((ext_vector_type(8))) short short8;
typedef __attribute__((ext_vector_type(4))) short short4v;
typedef __attribute__((ext_vector_type(4))) float f32x4;
typedef unsigned short u16;

__device__ __forceinline__ u16 f2bf(float f) {
    union { float f; unsigned u; } v; v.f = f;
    unsigned r = v.u + 0x7FFFu + ((v.u >> 16) & 1u);
    return (u16)(r >> 16);
}
__device__ __forceinline__ float bf2f(u16 h) {
    union { unsigned u; float f; } v; v.u = ((unsigned)h) << 16;
    return v.f;
}
__device__ __forceinline__ void split2(float f, u16& h, u16& l) {
    h = f2bf(f);
    l = f2bf(f - bf2f(h));
}
// 8-byte-aligned LDS frag load
__device__ __forceinline__ short8 ld8(const u16* p) {
    short4v a = *(const short4v*)p;
    short4v b = *(const short4v*)(p + 4);
    short8 r;
    r[0] = a[0]; r[1] = a[1]; r[2] = a[2]; r[3] = a[3];
    r[4] = b[0]; r[5] = b[1]; r[6] = b[2]; r[7] = b[3];
    return r;
}
#define MFMA(A, B, C) __builtin_amdgcn_mfma_f32_16x16x32_bf16(A, B, C, 0, 0, 0)

// ---------------- merged prep: zero A32 (u8 counts, 7.9MB) + all 8 weight splits ----------------
__global__ __launch_bounds__(256) void k_prep(int4* __restrict__ A32z, int nz4,
        const float* __restrict__ W1, u16* __restrict__ W1h, u16* __restrict__ W1l,
        const float* __restrict__ W2, u16* __restrict__ W2h, u16* __restrict__ W2l,
        const float* __restrict__ W3, u16* __restrict__ W3h, u16* __restrict__ W3l,
        const float* __restrict__ Wc1, u16* __restrict__ Wc1h, u16* __restrict__ Wc1l,
        const float* __restrict__ Wd, u16* __restrict__ WdTh, u16* __restrict__ WdTl,
        const float* __restrict__ Wc2, u16* __restrict__ Wc2Th, u16* __restrict__ Wc2Tl,
        const float* __restrict__ Wm1, u16* __restrict__ Wm1Th, u16* __restrict__ Wm1Tl,
        const float* __restrict__ Wm2, u16* __restrict__ Wm2Th, u16* __restrict__ Wm2Tl) {
    int i = blockIdx.x * 256 + threadIdx.x;
    if (i < nz4) { A32z[i] = make_int4(0, 0, 0, 0); return; }
    i -= nz4;
    const float* W; u16 *th, *tl; int K, F, Kp;
    if (i < 6144)        { W = W1;  th = W1h;  tl = W1l;  K = 78;   F = 64;  Kp = 96; }
    else if (i < 14336)  { i -= 6144;   W = W2;  th = W2h;  tl = W2l;  K = 64;   F = 128; Kp = 64; }
    else if (i < 47104)  { i -= 14336;  W = W3;  th = W3h;  tl = W3l;  K = 128;  F = 256; Kp = 128; }
    else if (i < 178176) { i -= 47104;  W = Wc1; th = Wc1h; tl = Wc1l; K = 1000; F = 128; Kp = 1024; }
    else if (i < 194560) { i -= 178176; W = Wd;  th = WdTh; tl = WdTl; K = 256;  F = 64;  Kp = 256; }
    else if (i < 202752) { i -= 194560; W = Wc2; th = Wc2Th; tl = Wc2Tl; K = 128; F = 64; Kp = 128; }
    else if (i < 210944) { i -= 202752; W = Wm1; th = Wm1Th; tl = Wm1Tl; K = 128; F = 64; Kp = 128; }
    else if (i < 212992) { i -= 210944; W = Wm2; th = Wm2Th; tl = Wm2Tl; K = 64;  F = 32; Kp = 64; }
    else return;
    int f = i / Kp, k = i - f * Kp;
    float v = (k < K) ? W[(size_t)k * F + f] : 0.f;
    u16 h, l; split2(v, h, l);
    th[i] = h; tl[i] = l;
}

// per-graph 30x32 adjacency count matrix, u8 packed 4-per-u32 (random global atomics).
// max per-cell count ~6 (Binomial(~122, 1/900)) => u8 safe. 7.9MB working set (was 15.7).
__global__ void k_cnt(const int* __restrict__ ei, unsigned* __restrict__ A32, int E) {
    int e = blockIdx.x * 256 + threadIdx.x;
    if (e >= E) return;
    int s = ei[e], d = ei[E + e];
    int g = d / 30;
    int idx = g * 960 + (d - g * 30) * 32 + (s - g * 30);
    atomicAdd(&A32[idx >> 2], 1u << ((idx & 3) * 8));
}

// ---------------- fused node pipeline + cell1 GEMM in one dispatch ----------------
// blocks [0, CELLB): cell1 = relu(cf @ Wc1 + bc1), 64 rows/block
// blocks [CELLB, CELLB+B): GCN node pipeline, one graph per block
__global__ __launch_bounds__(512, 8) void k_nodecell(
    const float* __restrict__ x, const unsigned* __restrict__ A32,
    const u16* __restrict__ W1h, const u16* __restrict__ W1l,
    const u16* __restrict__ W2h, const u16* __restrict__ W2l,
    const u16* __restrict__ W3h, const u16* __restrict__ W3l,
    const float* __restrict__ b1, const float* __restrict__ b2,
    const float* __restrict__ b3, float* __restrict__ P,
    const float* __restrict__ cf,
    const u16* __restrict__ Wc1h, const u16* __restrict__ Wc1l,
    const float* __restrict__ bc1, float* __restrict__ cell1,
    int CELLB) {
    __shared__ __align__(16) char smem[39936];
    int t = threadIdx.x;
    int wave = t >> 6, lane = t & 63, quad = lane >> 4, l15 = lane & 15;

    if (blockIdx.x < CELLB) {
        // ---- cell path: 64 rows x 128 cols, K=1000 padded 1024 in 128-chunks ----
        u16* Xh = (u16*)(smem + 0);
        u16* Xl = (u16*)(smem + 17920);
        int row0 = blockIdx.x * 64;
        int half = wave >> 2, wq = wave & 3;
        f32x4 acc[2][2] = {{{0.f,0.f,0.f,0.f},{0.f,0.f,0.f,0.f}},
                           {{0.f,0.f,0.f,0.f},{0.f,0.f,0.f,0.f}}};
        for (int ko = 0; ko < 8; ko++) {
#pragma unroll
            for (int ii = 0; ii < 4; ii++) {
                int i = t + ii * 512;          // float4 slot
                int r = i >> 5, c4 = i & 31;
                int col = ko * 128 + c4 * 4;
                float4 v = {0.f, 0.f, 0.f, 0.f};
                if (col < 1000) v = *(const float4*)(cf + (size_t)(row0 + r) * 1000 + col);
                float vv[4] = {v.x, v.y, v.z, v.w};
                short4v hs, ls;
#pragma unroll
                for (int j = 0; j < 4; j++) {
                    u16 h, l; split2(vv[j], h, l);
                    hs[j] = (short)h; ls[j] = (short)l;
                }
                *(short4v*)(Xh + r * 140 + c4 * 4) = hs;
                *(short4v*)(Xl + r * 140 + c4 * 4) = ls;
            }
            __syncthreads();
#pragma unroll
            for (int kk = 0; kk < 4; kk++) {
                int klo = kk * 32 + quad * 8;
                short8 ah[2], al[2];
#pragma unroll
                for (int mi = 0; mi < 2; mi++) {
                    ah[mi] = ld8(&Xh[(half * 32 + mi * 16 + l15) * 140 + klo]);
                    al[mi] = ld8(&Xl[(half * 32 + mi * 16 + l15) * 140 + klo]);
                }
#pragma unroll
                for (int ni = 0; ni < 2; ni++) {
                    int col = wq * 32 + ni * 16 + l15;
                    size_t o = (size_t)col * 1024 + ko * 128 + kk * 32 + quad * 8;
                    short8 bh = *(const short8*)(Wc1h + o);
                    short8 bl = *(const short8*)(Wc1l + o);
#pragma unroll
                    for (int mi = 0; mi < 2; mi++) {
                        acc[mi][ni] = MFMA(ah[mi], bh, acc[mi][ni]);
                        acc[mi][ni] = MFMA(al[mi], bh, acc[mi][ni]);
                        acc[mi][ni] = MFMA(ah[mi], bl, acc[mi][ni]);
                    }
                }
            }
            __syncthreads();
        }
#pragma unroll
        for (int ni = 0; ni < 2; ni++) {
            int col = wq * 32 + ni * 16 + l15;
            float bv = bc1[col];
#pragma unroll
            for (int mi = 0; mi < 2; mi++)
#pragma unroll
                for (int rg = 0; rg < 4; rg++) {
                    int row = row0 + half * 32 + mi * 16 + quad * 4 + rg;
                    cell1[(size_t)row * 128 + col] = fmaxf(acc[mi][ni][rg] + bv, 0.f);
                }
        }
        return;
    }

    // ---- node path (verbatim from verified kernel; u8-count unpack in Ph1) ----
    int g = blockIdx.x - CELLB;
    u16* xh  = (u16*)(smem + 0);
    u16* xl  = (u16*)(smem + 6400);
    u16* h1h = (u16*)(smem + 0);
    u16* h1l = (u16*)(smem + 4352);
    u16* a3h = (u16*)(smem + 0);
    u16* a3l = (u16*)(smem + 8448);
    float* Afp = (float*)(smem + 16896);
    float* dv  = (float*)(smem + 20736);
    u16* t1h = (u16*)(smem + 16896);
    u16* t1l = (u16*)(smem + 21504);
    u16* h2h = (u16*)(smem + 16896);
    u16* h2l = (u16*)(smem + 26112);
    u16* Ah  = (u16*)(smem + 35328);
    u16* Al  = (u16*)(smem + 37632);

    // Ph1: zero x pads; stage x split; stage Afp (u8 unpack); dv from global counts
    {
        for (int i = t; i < 860; i += 512) {
            uint* arr = (uint*)((i >= 430) ? (char*)xl : (char*)xh);
            int j = (i >= 430) ? i - 430 : i;
            int r, c32;
            if (j < 330) { r = j / 11; c32 = 39 + j % 11; }
            else { r = 30 + (j - 330) / 50; c32 = (j - 330) % 50; }
            arr[r * 50 + c32] = 0;
        }
        const float4* xg = (const float4*)(x + (size_t)g * 2340);
        for (int i = t; i < 585; i += 512) {
            float4 v = xg[i];
            int base = i * 4;
            float vv[4] = {v.x, v.y, v.z, v.w};
#pragma unroll
            for (int j = 0; j < 4; j++) {
                int idx = base + j;
                int r = idx / 78, c = idx - r * 78;
                u16 h, l; split2(vv[j], h, l);
                xh[r * 100 + c] = h; xl[r * 100 + c] = l;
            }
        }
        const unsigned* ac = A32 + (size_t)g * 240;
        if (t < 240) {
            unsigned w = ac[t];
            Afp[4 * t]     = (float)(w & 0xFFu);
            Afp[4 * t + 1] = (float)((w >> 8) & 0xFFu);
            Afp[4 * t + 2] = (float)((w >> 16) & 0xFFu);
            Afp[4 * t + 3] = (float)(w >> 24);
        }
        if (t >= 480 && t < 512) {
            int r = t - 480;
            float s = 1.f;
            if (r < 30) {
                const unsigned* rp = ac + r * 8;
                unsigned acc = 0;
#pragma unroll
                for (int j = 0; j < 8; j++) {
                    unsigned w = rp[j];
                    acc += (w & 0xFFu) + ((w >> 8) & 0xFFu) + ((w >> 16) & 0xFFu) + (w >> 24);
                }
                s += (float)acc;
            }
            dv[r] = (r < 30) ? rsqrtf(s) : 0.f;
        }
    }
    __syncthreads();
    // Ph3: A = (cnt + I) * dv_d * dv_s -> Ah/Al
    {
#pragma unroll
        for (int ii = 0; ii < 2; ii++) {
            int i = t + ii * 512;
            int r = i >> 5, c = i & 31;
            float a = 0.f;
            if (r < 30 && c < 30)
                a = (Afp[r * 32 + c] + (r == c ? 1.f : 0.f)) * dv[r] * dv[c];
            u16 h, l; split2(a, h, l);
            Ah[r * 36 + c] = h; Al[r * 36 + c] = l;
        }
    }
    __syncthreads();
    // Ph4: GEMM1  t1 = x @ W1  (M=32, N=64, K=96) -> t1T
    {
        int wm = wave >> 2, wn = wave & 3;
        int arow = wm * 16 + l15;
        int col = wn * 16 + l15;
        const u16* wph = W1h + col * 96 + quad * 8;
        const u16* wpl = W1l + col * 96 + quad * 8;
        f32x4 acc = {0.f, 0.f, 0.f, 0.f};
#pragma unroll
        for (int ch = 0; ch < 3; ch++) {
            int kc = ch * 32;
            short8 bh = *(const short8*)(wph + kc);
            short8 bl = *(const short8*)(wpl + kc);
            short8 ah = ld8(&xh[arow * 100 + kc + quad * 8]);
            short8 al = ld8(&xl[arow * 100 + kc + quad * 8]);
            acc = MFMA(ah, bh, acc);
            acc = MFMA(al, bh, acc);
            acc = MFMA(ah, bl, acc);
        }
#pragma unroll
        for (int rg = 0; rg < 4; rg++) {
            int row = wm * 16 + quad * 4 + rg;
            u16 h, l; split2(acc[rg], h, l);
            t1h[col * 36 + row] = h;
            t1l[col * 36 + row] = l;
        }
    }
    __syncthreads();
    // Ph5: agg1  h1 = relu(A @ t1 + b1)  (M=32, N=64, K=32)
    {
        int wm = wave >> 2, wn = wave & 3;
        int arow = wm * 16 + l15;
        int col = wn * 16 + l15;
        short8 aAh = ld8(&Ah[arow * 36 + quad * 8]);
        short8 aAl = ld8(&Al[arow * 36 + quad * 8]);
        short8 bh = ld8(&t1h[col * 36 + quad * 8]);
        short8 bl = ld8(&t1l[col * 36 + quad * 8]);
        f32x4 acc = {0.f, 0.f, 0.f, 0.f};
        acc = MFMA(aAh, bh, acc);
        acc = MFMA(aAl, bh, acc);
        acc = MFMA(aAh, bl, acc);
        float bb = b1[col];
#pragma unroll
        for (int rg = 0; rg < 4; rg++) {
            int row = wm * 16 + quad * 4 + rg;
            float v = fmaxf(acc[rg] + bb, 0.f);
            u16 h, l; split2(v, h, l);
            h1h[row * 68 + col] = h;
            h1l[row * 68 + col] = l;
        }
    }
    __syncthreads();
    // Ph6: GEMM2  h2 = relu(h1 @ W2 + b2)  (M=32, N=128, K=64) -> h2T
    {
        int col = wave * 16 + l15;
        const u16* wph = W2h + col * 64 + quad * 8;
        const u16* wpl = W2l + col * 64 + quad * 8;
        f32x4 acc[2] = {{0.f,0.f,0.f,0.f},{0.f,0.f,0.f,0.f}};
#pragma unroll
        for (int ch = 0; ch < 2; ch++) {
            int kc = ch * 32;
            short8 bh = *(const short8*)(wph + kc);
            short8 bl = *(const short8*)(wpl + kc);
#pragma unroll
            for (int mi = 0; mi < 2; mi++) {
                short8 ah = ld8(&h1h[(mi * 16 + l15) * 68 + kc + quad * 8]);
                short8 al = ld8(&h1l[(mi * 16 + l15) * 68 + kc + quad * 8]);
                acc[mi] = MFMA(ah, bh, acc[mi]);
                acc[mi] = MFMA(al, bh, acc[mi]);
                acc[mi] = MFMA(ah, bl, acc[mi]);
            }
        }
        float bb = b2[col];
#pragma unroll
        for (int mi = 0; mi < 2; mi++)
#pragma unroll
            for (int rg = 0; rg < 4; rg++) {
                int row = mi * 16 + quad * 4 + rg;
                float v = fmaxf(acc[mi][rg] + bb, 0.f);
                u16 h, l; split2(v, h, l);
                h2h[col * 36 + row] = h;
                h2l[col * 36 + row] = l;
            }
    }
    __syncthreads();
    // Ph7: agg2  a3 = A @ h2  (M=32, N=128, K=32)
    {
        int col = wave * 16 + l15;
        short8 bh = ld8(&h2h[col * 36 + quad * 8]);
        short8 bl = ld8(&h2l[col * 36 + quad * 8]);
        f32x4 acc[2] = {{0.f,0.f,0.f,0.f},{0.f,0.f,0.f,0.f}};
#pragma unroll
        for (int mi = 0; mi < 2; mi++) {
            short8 aAh = ld8(&Ah[(mi * 16 + l15) * 36 + quad * 8]);
            short8 aAl = ld8(&Al[(mi * 16 + l15) * 36 + quad * 8]);
            acc[mi] = MFMA(aAh, bh, acc[mi]);
            acc[mi] = MFMA(aAl, bh, acc[mi]);
            acc[mi] = MFMA(aAh, bl, acc[mi]);
        }
#pragma unroll
        for (int mi = 0; mi < 2; mi++)
#pragma unroll
            for (int rg = 0; rg < 4; rg++) {
                int row = mi * 16 + quad * 4 + rg;
                u16 h, l; split2(acc[mi][rg], h, l);
                a3h[row * 132 + col] = h;
                a3l[row * 132 + col] = l;
            }
    }
    __syncthreads();
    // Ph8: GEMM3 + pool (M=32, N=256, K=128)
    {
        int colb = wave * 32;
        f32x4 acc[2][2] = {{{0.f,0.f,0.f,0.f},{0.f,0.f,0.f,0.f}},
                           {{0.f,0.f,0.f,0.f},{0.f,0.f,0.f,0.f}}};
        short8 cwh[2], cwl[2], nwh[2], nwl[2];
#pragma unroll
        for (int ni = 0; ni < 2; ni++) {
            size_t o = (size_t)(colb + ni * 16 + l15) * 128 + quad * 8;
            cwh[ni] = *(const short8*)(W3h + o);
            cwl[ni] = *(const short8*)(W3l + o);
        }
#pragma unroll
        for (int ch = 0; ch < 4; ch++) {
            if (ch < 3) {
#pragma unroll
                for (int ni = 0; ni < 2; ni++) {
                    size_t o = (size_t)(colb + ni * 16 + l15) * 128 + (ch + 1) * 32 + quad * 8;
                    nwh[ni] = *(const short8*)(W3h + o);
                    nwl[ni] = *(const short8*)(W3l + o);
                }
            }
            short8 ah[2], al[2];
#pragma unroll
            for (int mi = 0; mi < 2; mi++) {
                ah[mi] = ld8(&a3h[(mi * 16 + l15) * 132 + ch * 32 + quad * 8]);
                al[mi] = ld8(&a3l[(mi * 16 + l15) * 132 + ch * 32 + quad * 8]);
            }
#pragma unroll
            for (int mi = 0; mi < 2; mi++)
#pragma unroll
                for (int ni = 0; ni < 2; ni++) {
                    acc[mi][ni] = MFMA(ah[mi], cwh[ni], acc[mi][ni]);
                    acc[mi][ni] = MFMA(al[mi], cwh[ni], acc[mi][ni]);
                    acc[mi][ni] = MFMA(ah[mi], cwl[ni], acc[mi][ni]);
                }
            if (ch < 3) {
#pragma unroll
                for (int ni = 0; ni < 2; ni++) { cwh[ni] = nwh[ni]; cwl[ni] = nwl[ni]; }
            }
        }
#pragma unroll
        for (int ni = 0; ni < 2; ni++) {
            int col = colb + ni * 16 + l15;
            float bb = b3[col];
            float p = 0.f;
#pragma unroll
            for (int mi = 0; mi < 2; mi++)
#pragma unroll
                for (int rg = 0; rg < 4; rg++) {
                    int row = mi * 16 + quad * 4 + rg;
                    if (row < 30) p += fmaxf(acc[mi][ni][rg] + bb, 0.f);
                }
            p += __shfl_down(p, 32);
            p += __shfl_down(p, 16);
            if (lane < 16)
                P[(size_t)g * 256 + colb + ni * 16 + lane] = p * (1.0f / 30.0f);
        }
    }
}

// ---------------- MFMA tail: drug embed + cell2 + combiner head, 32 graphs/block ----------------
__global__ __launch_bounds__(256) void k_tail2(const float* __restrict__ pooled,
        const float* __restrict__ cell1,
        const u16* __restrict__ WdTh, const u16* __restrict__ WdTl, const float* __restrict__ bd,
        const u16* __restrict__ Wc2Th, const u16* __restrict__ Wc2Tl, const float* __restrict__ bc2,
        const u16* __restrict__ Wm1Th, const u16* __restrict__ Wm1Tl, const float* __restrict__ bm1,
        const u16* __restrict__ Wm2Th, const u16* __restrict__ Wm2Tl, const float* __restrict__ bm2,
        const float* __restrict__ Wo, const float* __restrict__ bo,
        float* __restrict__ out) {
    __shared__ __align__(16) char smem[50176];
    u16* Xh  = (u16*)(smem);
    u16* Xl  = (u16*)(smem + 25088);
    u16* dzh = (u16*)(smem);
    u16* dzl = (u16*)(smem + 8960);
    u16* z1h = (u16*)(smem + 17920);
    u16* z1l = (u16*)(smem + 22528);
    float* z2f = (float*)(smem + 27136);
    int t = threadIdx.x;
    int row0 = blockIdx.x * 32;
    int wave = t >> 6, lane = t & 63, quad = lane >> 4, l15 = lane & 15;

    // stage X = [pooled | cell1] split (32 rows x 96 float4)
#pragma unroll
    for (int ii = 0; ii < 12; ii++) {
        int i = t + ii * 256;
        int r = i / 96, c4 = i - r * 96;
        float4 v = (c4 < 64)
            ? ((const float4*)(pooled + (size_t)(row0 + r) * 256))[c4]
            : ((const float4*)(cell1 + (size_t)(row0 + r) * 128))[c4 - 64];
        float vv[4] = {v.x, v.y, v.z, v.w};
        short4v hs, ls;
#pragma unroll
        for (int j = 0; j < 4; j++) {
            u16 h, l; split2(vv[j], h, l);
            hs[j] = (short)h; ls[j] = (short)l;
        }
        *(short4v*)(Xh + r * 392 + c4 * 4) = hs;
        *(short4v*)(Xl + r * 392 + c4 * 4) = ls;
    }
    __syncthreads();

    // G1: waves 0,1 -> drug (K=256); waves 2,3 -> cellz (K=128)
    bool cw = wave >= 2;
    int nbase = (wave & 1) * 32;
    const u16* Bh = cw ? Wc2Th : WdTh;
    const u16* Bl = cw ? Wc2Tl : WdTl;
    const int Kp = cw ? 128 : 256;
    const int nch = cw ? 4 : 8;
    const int acol = cw ? 256 : 0;
    f32x4 acc[2][2] = {{{0.f,0.f,0.f,0.f},{0.f,0.f,0.f,0.f}},
                       {{0.f,0.f,0.f,0.f},{0.f,0.f,0.f,0.f}}};
    for (int ch = 0; ch < nch; ch++) {
        int kc = ch * 32 + quad * 8;
        short8 ah[2], al[2];
#pragma unroll
        for (int mi = 0; mi < 2; mi++) {
            ah[mi] = ld8(&Xh[(mi * 16 + l15) * 392 + acol + kc]);
            al[mi] = ld8(&Xl[(mi * 16 + l15) * 392 + acol + kc]);
        }
#pragma unroll
        for (int ni = 0; ni < 2; ni++) {
            int col = nbase + ni * 16 + l15;
            short8 bh = *(const short8*)(Bh + (size_t)col * Kp + kc);
            short8 bl = *(const short8*)(Bl + (size_t)col * Kp + kc);
#pragma unroll
            for (int mi = 0; mi < 2; mi++) {
                acc[mi][ni] = MFMA(ah[mi], bh, acc[mi][ni]);
                acc[mi][ni] = MFMA(al[mi], bh, acc[mi][ni]);
                acc[mi][ni] = MFMA(ah[mi], bl, acc[mi][ni]);
            }
        }
    }
    __syncthreads();
#pragma unroll
    for (int ni = 0; ni < 2; ni++) {
        int c = nbase + ni * 16 + l15;
        float bb = cw ? bc2[c] : bd[c];
        int col = (cw ? 64 : 0) + c;
#pragma unroll
        for (int mi = 0; mi < 2; mi++)
#pragma unroll
            for (int rg = 0; rg < 4; rg++) {
                int row = mi * 16 + quad * 4 + rg;
                u16 h, l; split2(acc[mi][ni][rg] + bb, h, l);
                dzh[row * 140 + col] = h;
                dzl[row * 140 + col] = l;
            }
    }
    __syncthreads();

    // G2: z1 = relu(dz @ Wm1T + bm1)  (M=32, N=64, K=128)
    {
        int col = wave * 16 + l15;
        f32x4 a2[2] = {{0.f,0.f,0.f,0.f},{0.f,0.f,0.f,0.f}};
#pragma unroll
        for (int ch = 0; ch < 4; ch++) {
            int kc = ch * 32 + quad * 8;
            short8 bh = *(const short8*)(Wm1Th + (size_t)col * 128 + kc);
            short8 bl = *(const short8*)(Wm1Tl + (size_t)col * 128 + kc);
#pragma unroll
            for (int mi = 0; mi < 2; mi++) {
                short8 ah = ld8(&dzh[(mi * 16 + l15) * 140 + kc]);
                short8 al = ld8(&dzl[(mi * 16 + l15) * 140 + kc]);
                a2[mi] = MFMA(ah, bh, a2[mi]);
                a2[mi] = MFMA(al, bh, a2[mi]);
                a2[mi] = MFMA(ah, bl, a2[mi]);
            }
        }
        float bb = bm1[col];
#pragma unroll
        for (int mi = 0; mi < 2; mi++)
#pragma unroll
            for (int rg = 0; rg < 4; rg++) {
                int row = mi * 16 + quad * 4 + rg;
                u16 h, l; split2(fmaxf(a2[mi][rg] + bb, 0.f), h, l);
                z1h[row * 72 + col] = h;
                z1l[row * 72 + col] = l;
            }
    }
    __syncthreads();

    // G3: z2 = relu(z1 @ Wm2T + bm2)  (M=32, N=32, K=64); waves 0,1
    if (wave < 2) {
        int col = wave * 16 + l15;
        f32x4 a3[2] = {{0.f,0.f,0.f,0.f},{0.f,0.f,0.f,0.f}};
#pragma unroll
        for (int ch = 0; ch < 2; ch++) {
            int kc = ch * 32 + quad * 8;
            short8 bh = *(const short8*)(Wm2Th + (size_t)col * 64 + kc);
            short8 bl = *(const short8*)(Wm2Tl + (size_t)col * 64 + kc);
#pragma unroll
            for (int mi = 0; mi < 2; mi++) {
                short8 ah = ld8(&z1h[(mi * 16 + l15) * 72 + kc]);
                short8 al = ld8(&z1l[(mi * 16 + l15) * 72 + kc]);
                a3[mi] = MFMA(ah, bh, a3[mi]);
                a3[mi] = MFMA(al, bh, a3[mi]);
                a3[mi] = MFMA(ah, bl, a3[mi]);
            }
        }
        float bb = bm2[col];
#pragma unroll
        for (int mi = 0; mi < 2; mi++)
#pragma unroll
            for (int rg = 0; rg < 4; rg++) {
                int row = mi * 16 + quad * 4 + rg;
                z2f[row * 33 + col] = fmaxf(a3[mi][rg] + bb, 0.f);
            }
    }
    __syncthreads();

    // G4: out = z2 . Wo + bo (fp32)
    if (t < 32) {
        float s = bo[0];
#pragma unroll 8
        for (int k = 0; k < 32; k++) s += z2f[t * 33 + k] * Wo[k];
        out[row0 + t] = s;
    }
}

// ---------------- launch ----------------

extern "C" void kernel_launch(void* const* d_in, const int* in_sizes, int n_in,
                              void* d_out, int out_size, void* d_ws, size_t ws_size,
                              hipStream_t stream) {
    const float* x   = (const float*)d_in[0];
    const int*   ei  = (const int*)d_in[1];
    const float* cf  = (const float*)d_in[3];
    const float* W1  = (const float*)d_in[4];
    const float* b1  = (const float*)d_in[5];
    const float* W2  = (const float*)d_in[6];
    const float* b2  = (const float*)d_in[7];
    const float* W3  = (const float*)d_in[8];
    const float* b3  = (const float*)d_in[9];
    const float* Wd  = (const float*)d_in[10];
    const float* bd  = (const float*)d_in[11];
    const float* Wc1 = (const float*)d_in[12];
    const float* bc1 = (const float*)d_in[13];
    const float* Wc2 = (const float*)d_in[14];
    const float* bc2 = (const float*)d_in[15];
    const float* Wm1 = (const float*)d_in[16];
    const float* bm1 = (const float*)d_in[17];
    const float* Wm2 = (const float*)d_in[18];
    const float* bm2 = (const float*)d_in[19];
    const float* Wo  = (const float*)d_in[20];
    const float* bo  = (const float*)d_in[21];
    float* out = (float*)d_out;

    const int E = in_sizes[1] / 2;     // 1,000,000
    const int B = in_sizes[3] / 1000;  // 8192

    char* w = (char*)d_ws;
    auto carve = [&](size_t bytes) { void* p = (void*)w; w += (bytes + 255) & ~(size_t)255; return p; };
    unsigned* A32 = (unsigned*)carve((size_t)B * 960);       // u8 counts, 7.9 MB
    float* pooled = (float*)carve((size_t)B * 256 * 4);
    float* cell1  = (float*)carve((size_t)B * 128 * 4);
    u16* W1th = (u16*)carve(64 * 96 * 2);     u16* W1tl = (u16*)carve(64 * 96 * 2);
    u16* W2th = (u16*)carve(128 * 64 * 2);    u16* W2tl = (u16*)carve(128 * 64 * 2);
    u16* W3th = (u16*)carve(256 * 128 * 2);   u16* W3tl = (u16*)carve(256 * 128 * 2);
    u16* Wc1th = (u16*)carve(128 * 1024 * 2); u16* Wc1tl = (u16*)carve(128 * 1024 * 2);
    u16* WdTh = (u16*)carve(64 * 256 * 2);    u16* WdTl = (u16*)carve(64 * 256 * 2);
    u16* Wc2Th = (u16*)carve(64 * 128 * 2);   u16* Wc2Tl = (u16*)carve(64 * 128 * 2);
    u16* Wm1Th = (u16*)carve(64 * 128 * 2);   u16* Wm1Tl = (u16*)carve(64 * 128 * 2);
    u16* Wm2Th = (u16*)carve(32 * 64 * 2);    u16* Wm2Tl = (u16*)carve(32 * 64 * 2);

    auto g1 = [](int n) { return (n + 255) / 256; };

    const int nz4 = B * 60;                // int4 slots to zero (7.9 MB)
    const int nsplit = 212992;

    // 1) merged prep: zero adjacency + all weight splits
    k_prep<<<g1(nz4 + nsplit), 256, 0, stream>>>((int4*)A32, nz4,
        W1, W1th, W1tl, W2, W2th, W2tl, W3, W3th, W3tl, Wc1, Wc1th, Wc1tl,
        Wd, WdTh, WdTl, Wc2, Wc2Th, Wc2Tl, Wm1, Wm1Th, Wm1Tl, Wm2, Wm2Th, Wm2Tl);

    // 2) edge counting (random global atomics, u8-packed: half the footprint)
    k_cnt<<<g1(E), 256, 0, stream>>>(ei, A32, E);

    // 3) fused GCN pipeline + cell1 GEMM in one dispatch (cell blocks first)
    const int CELLB = B / 64;              // 128 blocks x 64 rows
    k_nodecell<<<CELLB + B, 512, 0, stream>>>(x, A32,
                                  W1th, W1tl, W2th, W2tl, W3th, W3tl,
                                  b1, b2, b3, pooled,
                                  cf, Wc1th, Wc1tl, bc1, cell1, CELLB);

    // 4) MFMA tail: drug embed + cell2 + combiner head
    k_tail2<<<B / 32, 256, 0, stream>>>(pooled, cell1,
                                        WdTh, WdTl, bd, Wc2Th, Wc2Tl, bc2,
                                        Wm1Th, Wm1Tl, bm1, Wm2Th, Wm2Tl, bm2,
                                        Wo, bo, out);
}